// Round 3
// baseline (3620.486 us; speedup 1.0000x reference)
//
#include <hip/hip_runtime.h>
#include <stdint.h>

typedef __bf16 bf16x8 __attribute__((ext_vector_type(8)));
typedef float  f32x4  __attribute__((ext_vector_type(4)));
typedef unsigned short ushortx4 __attribute__((ext_vector_type(4)));

// LDS layout (bytes) — 103936 total, 1 block/CU, 16 waves
#define LDS_NFROW 0        // nf row-major [128][128] bf16, swizzled
#define LDS_NFT   32768    // nf^T        [128][128] bf16, swizzled
#define LDS_P     65536    // P = A@nf    [128][128] bf16, swizzled (also MLP h1)
#define LDS_RSA   98304    // adjacency row sums, 128 f32
#define LDS_CB    98816    // combined GRU bias constants [128][8] f32
#define LDS_MB1   102912   // mb1 128 f32
#define LDS_MB2   103424   // mb2 128 f32
#define LDS_TOTAL 103936

// ws layout (bytes)
#define WS_GW2T   0        // bf16 [384][128]  (gnn_w @ W_ih^T)^T rows
#define WS_WHH    98304    // bf16 [384][128]
#define WS_MW1    196608   // bf16 [128][128]
#define WS_MW2    229376   // bf16 [128][128]
#define WS_GB2    262144   // f32  [384]       W_ih @ gnn_b

__device__ __forceinline__ unsigned short f2bf(float f){
  union{float f; uint32_t u;} v; v.f = f;
  return (unsigned short)((v.u + 0x7FFFu + ((v.u>>16)&1u)) >> 16);
}
__device__ __forceinline__ float bf2f(unsigned short h){
  union{uint32_t u; float f;} v; v.u = ((uint32_t)h)<<16; return v.f;
}
__device__ __forceinline__ float fast_sigmoid(float x){
  float t = __builtin_amdgcn_exp2f(-1.442695041f*x);
  return __builtin_amdgcn_rcpf(1.0f + t);
}
__device__ __forceinline__ float fast_tanh(float x){
  float t = __builtin_amdgcn_exp2f(-2.885390082f*x);
  return 2.0f*__builtin_amdgcn_rcpf(1.0f + t) - 1.0f;
}
// XOR-swizzled row-major [128][128] bf16 LDS addressing. 16B chunks of 8 elems.
// chunk ^= (row&7) ^ ((row>>3)&3): row-contiguous b128 reads conflict-free AND
// column-scatter (rows spaced 4/8 apart) lands on distinct chunks/banks.
__device__ __forceinline__ uint32_t sw(uint32_t row, uint32_t col){
  return row*256u + ((((col>>3) ^ (row&7) ^ ((row>>3)&3)) << 4) | ((col&7)<<1));
}

// ---------------- prep kernel: weight conversions + Gw2T + gb2 ----------------
extern "C" __global__ __launch_bounds__(128) void gnn_prep(
    const float* __restrict__ Wih, const float* __restrict__ Whh,
    const float* __restrict__ gnnw, const float* __restrict__ gnnb,
    const float* __restrict__ mW1, const float* __restrict__ mW2,
    unsigned short* __restrict__ gw2t, unsigned short* __restrict__ whhb,
    unsigned short* __restrict__ mw1b, unsigned short* __restrict__ mw2b,
    float* __restrict__ gb2)
{
  __shared__ float wg[128];
  const int b = blockIdx.x, t = threadIdx.x;
  if (b < 384){
    wg[t] = Wih[b*128 + t];
    __syncthreads();
    float acc = 0.f;
    for (int h=0; h<128; ++h) acc += wg[h] * gnnw[t*128 + h];
    gw2t[b*128 + t] = f2bf(acc);
    if (t == 0){
      float a2 = 0.f;
      for (int h=0; h<128; ++h) a2 += wg[h] * gnnb[h];
      gb2[b] = a2;
    }
  } else if (b < 416){
    int base = (b-384)*1536;
    for (int i=t; i<1536; i+=128) whhb[base+i] = f2bf(Whh[base+i]);
  } else if (b < 432){
    int base = (b-416)*1024;
    for (int i=t; i<1024; i+=128) mw1b[base+i] = f2bf(mW1[base+i]);
  } else if (b < 448){
    int base = (b-432)*1024;
    for (int i=t; i<1024; i+=128) mw2b[base+i] = f2bf(mW2[base+i]);
  }
}

// ---------------- main fused kernel: one 1024-thread block per sentence ----------------
extern "C" __global__ __launch_bounds__(1024) void gnn_main(
    const int* __restrict__ iv, const float* __restrict__ adj,
    const float* __restrict__ emb,
    const float* __restrict__ bih, const float* __restrict__ bhh,
    const float* __restrict__ mb1, const float* __restrict__ mb2,
    const float* __restrict__ mW3, const float* __restrict__ mb3,
    const __bf16* __restrict__ gw2t, const __bf16* __restrict__ whhb,
    const __bf16* __restrict__ mw1b, const __bf16* __restrict__ mw2b,
    const float* __restrict__ gb2, float* __restrict__ out)
{
  extern __shared__ char lds[];
  const int bs   = blockIdx.x;
  const int tid  = threadIdx.x;
  const int w    = tid >> 6;        // 0..15
  const int lane = tid & 63;
  const int n16  = lane & 15;
  const int q    = lane >> 4;
  const f32x4 zf4 = {0.f, 0.f, 0.f, 0.f};

  // wave roles
  const int hw = w >> 1, lc = w & 1;
  const int t0  = hw*16;            // stage-A t-tile / gate-upd h-block
  const int h0  = t0;
  const int lG0 = lc*64;            // gate/upd l-range [lG0, lG0+64)
  const int wr = w >> 2, wc = w & 3;
  const int tm0 = wr*32, lm0 = wc*32;   // MLP tile origins

  // ---- init: biases / emb gather / rowsums ----
  if (tid < 128){
    int h = tid;
    float* cb = (float*)(lds + LDS_CB + h*32);
    cb[0] = gb2[h]; cb[1] = gb2[128+h]; cb[2] = gb2[256+h];
    cb[3] = bih[h] + bhh[h];
    cb[4] = bih[128+h] + bhh[128+h];
    cb[5] = bih[256+h];
    cb[6] = bhh[256+h];
    cb[7] = 0.f;
  } else if (tid < 256){
    int t = tid - 128;
    *(float*)(lds + LDS_MB1 + t*4) = mb1[t];
    *(float*)(lds + LDS_MB2 + t*4) = mb2[t];
  }
  {
    const int l   = tid >> 3;
    const int hc8 = (tid & 7) * 16;
    const int row = iv[bs*128 + l];
    const float* src = emb + (size_t)row*128 + hc8;
    #pragma unroll
    for (int c=0; c<2; ++c){
      float4 f0 = *(const float4*)(src + c*8);
      float4 f1 = *(const float4*)(src + c*8 + 4);
      union{ bf16x8 v; unsigned short s8[8]; } u;
      u.s8[0]=f2bf(f0.x); u.s8[1]=f2bf(f0.y); u.s8[2]=f2bf(f0.z); u.s8[3]=f2bf(f0.w);
      u.s8[4]=f2bf(f1.x); u.s8[5]=f2bf(f1.y); u.s8[6]=f2bf(f1.z); u.s8[7]=f2bf(f1.w);
      *(bf16x8*)(lds + LDS_NFROW + sw(l, hc8 + c*8)) = u.v;
      #pragma unroll
      for (int j=0; j<8; ++j)
        *(unsigned short*)(lds + LDS_NFT + sw(hc8 + c*8 + j, l)) = u.s8[j];
    }
    // adjacency row sum (8 threads per row, 16 elems each)
    const float* ap = adj + (size_t)bs*16384 + l*128 + hc8;
    float s = 0.f;
    #pragma unroll
    for (int c=0; c<4; ++c){
      float4 f = *(const float4*)(ap + c*4);
      s += f.x + f.y + f.z + f.w;
    }
    s += __shfl_xor(s, 1);
    s += __shfl_xor(s, 2);
    s += __shfl_xor(s, 4);
    if ((tid & 7) == 0) *(float*)(lds + LDS_RSA + l*4) = s;
  }
  __syncthreads();

  // gate weight row base pointers (wave-uniform + n16)
  const __bf16* gR = gw2t + (size_t)(h0       + n16) * 128;
  const __bf16* gZ = gw2t + (size_t)(h0 + 128 + n16) * 128;
  const __bf16* gN = gw2t + (size_t)(h0 + 256 + n16) * 128;
  const __bf16* hR = whhb + (size_t)(h0       + n16) * 128;
  const __bf16* hZ = whhb + (size_t)(h0 + 128 + n16) * 128;
  const __bf16* hN = whhb + (size_t)(h0 + 256 + n16) * 128;
  const float*  abase = adj + (size_t)bs * 16384;

  for (int it=0; it<10; ++it){
    // ===== stage A: P^T[t][l] = sum_l' nf^T[t][l'] * adj[l][l'] =====
    // A-op = nf^T (LDS), B-op = adjacency rows straight from global fp32 (L2-hot)
    f32x4 accA[4];
    #pragma unroll
    for (int j=0; j<4; ++j) accA[j] = zf4;
    for (int ks=0; ks<4; ++ks){
      bf16x8 af = *(const bf16x8*)(lds + LDS_NFT + sw(t0 + n16, ks*32 + q*8));
      #pragma unroll
      for (int j=0; j<4; ++j){
        int al = lG0 + j*16 + n16;                 // B n-index -> adjacency row l
        const float* ap = abase + al*128 + ks*32 + q*8;
        float4 a0 = *(const float4*)(ap);
        float4 a1 = *(const float4*)(ap + 4);
        union{ bf16x8 v; unsigned short s8[8]; } u;
        u.s8[0]=f2bf(a0.x); u.s8[1]=f2bf(a0.y); u.s8[2]=f2bf(a0.z); u.s8[3]=f2bf(a0.w);
        u.s8[4]=f2bf(a1.x); u.s8[5]=f2bf(a1.y); u.s8[6]=f2bf(a1.z); u.s8[7]=f2bf(a1.w);
        accA[j] = __builtin_amdgcn_mfma_f32_16x16x32_bf16(af, u.v, accA[j], 0,0,0);
      }
    }
    #pragma unroll
    for (int j=0; j<4; ++j){
      int l = lG0 + j*16 + n16;
      ushortx4 o4;
      #pragma unroll
      for (int r=0; r<4; ++r) o4[r] = f2bf(accA[j][r]);
      *(ushortx4*)(lds + LDS_P + sw(l, t0 + q*4)) = o4;   // P[l][t]
    }
    __syncthreads();

    // ===== gate matmuls: wave = 16 h-rows x 64 l-cols, k-full =====
    f32x4 aR[4], aZ[4], aGN[4], aHN[4];
    #pragma unroll
    for (int i=0; i<4; ++i){ aR[i]=zf4; aZ[i]=zf4; aGN[i]=zf4; aHN[i]=zf4; }
    for (int ks=0; ks<4; ++ks){
      int koff = ks*32 + q*8;
      bf16x8 f_gr = *(const bf16x8*)(gR + koff);
      bf16x8 f_gz = *(const bf16x8*)(gZ + koff);
      bf16x8 f_gn = *(const bf16x8*)(gN + koff);
      bf16x8 f_hr = *(const bf16x8*)(hR + koff);
      bf16x8 f_hz = *(const bf16x8*)(hZ + koff);
      bf16x8 f_hn = *(const bf16x8*)(hN + koff);
      #pragma unroll
      for (int lt=0; lt<4; ++lt){
        int l = lG0 + lt*16 + n16;
        bf16x8 bp = *(const bf16x8*)(lds + LDS_P     + sw(l, koff));
        bf16x8 bh = *(const bf16x8*)(lds + LDS_NFROW + sw(l, koff));
        aR[lt]  = __builtin_amdgcn_mfma_f32_16x16x32_bf16(f_gr, bp, aR[lt], 0,0,0);
        aZ[lt]  = __builtin_amdgcn_mfma_f32_16x16x32_bf16(f_gz, bp, aZ[lt], 0,0,0);
        aGN[lt] = __builtin_amdgcn_mfma_f32_16x16x32_bf16(f_gn, bp, aGN[lt], 0,0,0);
        aR[lt]  = __builtin_amdgcn_mfma_f32_16x16x32_bf16(f_hr, bh, aR[lt], 0,0,0);
        aZ[lt]  = __builtin_amdgcn_mfma_f32_16x16x32_bf16(f_hz, bh, aZ[lt], 0,0,0);
        aHN[lt] = __builtin_amdgcn_mfma_f32_16x16x32_bf16(f_hn, bh, aHN[lt], 0,0,0);
      }
    }
    __syncthreads();   // all gate reads of NFROW/P done before nf updates

    // ===== elementwise GRU update =====
    f32x4 cbA[4], cbB[4];
    #pragma unroll
    for (int r=0; r<4; ++r){
      int h = h0 + q*4 + r;
      cbA[r] = *(const f32x4*)(lds + LDS_CB + h*32);
      cbB[r] = *(const f32x4*)(lds + LDS_CB + h*32 + 16);
    }
    #pragma unroll
    for (int lt=0; lt<4; ++lt){
      int l = lG0 + lt*16 + n16;
      float rs = *(const float*)(lds + LDS_RSA + l*4);
      uint32_t a_nf = sw(l, h0 + q*4);
      ushortx4 old4 = *(const ushortx4*)(lds + LDS_NFROW + a_nf);
      ushortx4 new4;
      #pragma unroll
      for (int r=0; r<4; ++r){
        float xr = aR[lt][r] + rs*cbA[r][0] + cbA[r][3];
        float xz = aZ[lt][r] + rs*cbA[r][1] + cbB[r][0];
        float rg = fast_sigmoid(xr);
        float zg = fast_sigmoid(xz);
        float xn = (aGN[lt][r] + rs*cbA[r][2] + cbB[r][1]) + rg*(aHN[lt][r] + cbB[r][2]);
        float ng = fast_tanh(xn);
        float hv = bf2f(old4[r]);
        new4[r] = f2bf(ng + zg*(hv - ng));
      }
      *(ushortx4*)(lds + LDS_NFROW + a_nf) = new4;
      #pragma unroll
      for (int r=0; r<4; ++r)
        *(unsigned short*)(lds + LDS_NFT + sw(h0 + q*4 + r, l)) = new4[r];
    }
    __syncthreads();
  }

  // ===== MLP: h1 = tanh(nf@mW1^T + mb1) -> LDS_P =====
  {
    f32x4 acc[2][2];
    #pragma unroll
    for (int a=0; a<2; ++a){ acc[a][0] = zf4; acc[a][1] = zf4; }
    for (int ks=0; ks<4; ++ks){
      int koff = ks*32 + q*8;
      bf16x8 af[2];
      #pragma unroll
      for (int tt=0; tt<2; ++tt)
        af[tt] = *(const bf16x8*)(mw1b + (size_t)(tm0 + tt*16 + n16)*128 + koff);
      #pragma unroll
      for (int lb=0; lb<2; ++lb){
        int l = lm0 + lb*16 + n16;
        bf16x8 bb = *(const bf16x8*)(lds + LDS_NFROW + sw(l, koff));
        #pragma unroll
        for (int tt=0; tt<2; ++tt)
          acc[tt][lb] = __builtin_amdgcn_mfma_f32_16x16x32_bf16(af[tt], bb, acc[tt][lb], 0,0,0);
      }
    }
    __syncthreads();  // NFROW reads done (not strictly needed; cheap safety for P write below)
    #pragma unroll
    for (int tt=0; tt<2; ++tt){
      #pragma unroll
      for (int lb=0; lb<2; ++lb){
        int l  = lm0 + lb*16 + n16;
        int ob = tm0 + tt*16 + q*4;
        ushortx4 o4;
        #pragma unroll
        for (int r=0; r<4; ++r){
          float bsv = *(const float*)(lds + LDS_MB1 + (ob + r)*4);
          o4[r] = f2bf(fast_tanh(acc[tt][lb][r] + bsv));
        }
        *(ushortx4*)(lds + LDS_P + sw(l, ob)) = o4;
      }
    }
  }
  __syncthreads();

  // ===== h2 = tanh(h1@mW2^T + mb2) -> LDS_NFT region =====
  {
    f32x4 acc[2][2];
    #pragma unroll
    for (int a=0; a<2; ++a){ acc[a][0] = zf4; acc[a][1] = zf4; }
    for (int ks=0; ks<4; ++ks){
      int koff = ks*32 + q*8;
      bf16x8 af[2];
      #pragma unroll
      for (int tt=0; tt<2; ++tt)
        af[tt] = *(const bf16x8*)(mw2b + (size_t)(tm0 + tt*16 + n16)*128 + koff);
      #pragma unroll
      for (int lb=0; lb<2; ++lb){
        int l = lm0 + lb*16 + n16;
        bf16x8 bb = *(const bf16x8*)(lds + LDS_P + sw(l, koff));
        #pragma unroll
        for (int tt=0; tt<2; ++tt)
          acc[tt][lb] = __builtin_amdgcn_mfma_f32_16x16x32_bf16(af[tt], bb, acc[tt][lb], 0,0,0);
      }
    }
    #pragma unroll
    for (int tt=0; tt<2; ++tt){
      #pragma unroll
      for (int lb=0; lb<2; ++lb){
        int l  = lm0 + lb*16 + n16;
        int ob = tm0 + tt*16 + q*4;
        ushortx4 o4;
        #pragma unroll
        for (int r=0; r<4; ++r){
          float bsv = *(const float*)(lds + LDS_MB2 + (ob + r)*4);
          o4[r] = f2bf(fast_tanh(acc[tt][lb][r] + bsv));
        }
        *(ushortx4*)(lds + LDS_NFT + sw(l, ob)) = o4;
      }
    }
  }
  __syncthreads();

  // ===== final: score[l] = tanh(h2[l]·mW3 + mb3) =====
  {
    int l = tid >> 3, p8 = tid & 7;
    float dot = 0.f;
    #pragma unroll
    for (int c=0; c<2; ++c){
      int o = p8*16 + c*8;
      union{ bf16x8 v; unsigned short s8[8]; } u;
      u.v = *(const bf16x8*)(lds + LDS_NFT + sw(l, o));
      float4 w0 = *(const float4*)(mW3 + o);
      float4 w1 = *(const float4*)(mW3 + o + 4);
      dot += bf2f(u.s8[0])*w0.x + bf2f(u.s8[1])*w0.y + bf2f(u.s8[2])*w0.z + bf2f(u.s8[3])*w0.w
           + bf2f(u.s8[4])*w1.x + bf2f(u.s8[5])*w1.y + bf2f(u.s8[6])*w1.z + bf2f(u.s8[7])*w1.w;
    }
    dot += __shfl_xor(dot, 1);
    dot += __shfl_xor(dot, 2);
    dot += __shfl_xor(dot, 4);
    if (p8 == 0) out[bs*128 + l] = fast_tanh(dot + mb3[0]);
  }
}

extern "C" void kernel_launch(void* const* d_in, const int* in_sizes, int n_in,
                              void* d_out, int out_size, void* d_ws, size_t ws_size,
                              hipStream_t stream)
{
  const int*   iv   = (const int*)  d_in[0];
  const float* adj  = (const float*)d_in[1];
  const float* emb  = (const float*)d_in[2];
  const float* gnnw = (const float*)d_in[3];
  const float* gnnb = (const float*)d_in[4];
  const float* Wih  = (const float*)d_in[5];
  const float* Whh  = (const float*)d_in[6];
  const float* bihp = (const float*)d_in[7];
  const float* bhhp = (const float*)d_in[8];
  const float* mW1  = (const float*)d_in[9];
  const float* mb1  = (const float*)d_in[10];
  const float* mW2  = (const float*)d_in[11];
  const float* mb2  = (const float*)d_in[12];
  const float* mW3  = (const float*)d_in[13];
  const float* mb3  = (const float*)d_in[14];
  float* out = (float*)d_out;

  char* ws = (char*)d_ws;
  unsigned short* gw2t_w = (unsigned short*)(ws + WS_GW2T);
  unsigned short* whhb_w = (unsigned short*)(ws + WS_WHH);
  unsigned short* mw1b_w = (unsigned short*)(ws + WS_MW1);
  unsigned short* mw2b_w = (unsigned short*)(ws + WS_MW2);
  float*          gb2_w  = (float*)(ws + WS_GB2);

  hipFuncSetAttribute((const void*)gnn_main,
                      hipFuncAttributeMaxDynamicSharedMemorySize, LDS_TOTAL);

  gnn_prep<<<448, 128, 0, stream>>>(Wih, Whh, gnnw, gnnb, mW1, mW2,
                                    gw2t_w, whhb_w, mw1b_w, mw2b_w, gb2_w);

  int nbs = in_sizes[0] / 128;  // B*S = 2048 sentences
  gnn_main<<<nbs, 1024, LDS_TOTAL, stream>>>(
      iv, adj, emb, bihp, bhhp, mb1, mb2, mW3, mb3,
      (const __bf16*)gw2t_w, (const __bf16*)whhb_w,
      (const __bf16*)mw1b_w, (const __bf16*)mw2b_w, gb2_w, out);
}

// Round 4
// 2364.925 us; speedup vs baseline: 1.5309x; 1.5309x over previous
//
#include <hip/hip_runtime.h>
#include <stdint.h>

typedef __bf16 bf16x8 __attribute__((ext_vector_type(8)));
typedef float  f32x4  __attribute__((ext_vector_type(4)));
typedef unsigned short ushortx4 __attribute__((ext_vector_type(4)));

// LDS layout (bytes) — 136704 total, 1 block/CU, 16 waves (4/SIMD)
#define LDS_NFROW 0        // nf row-major [128][128] bf16, swizzled
#define LDS_NFT   32768    // nf^T        [128][128] bf16, swizzled
#define LDS_P     65536    // P = A@nf    [128][128] bf16, swizzled (also MLP h1)
#define LDS_SAT   98304    // adjacency bf16, MFMA B-fragment order [32 chunks][64 lanes][16B]
#define LDS_RSA   131072   // adjacency row sums, 128 f32
#define LDS_CB    131584   // combined GRU bias constants [128][8] f32
#define LDS_MB1   135680   // mb1 128 f32
#define LDS_MB2   136192   // mb2 128 f32
#define LDS_TOTAL 136704

// ws layout (bytes)
#define WS_GW2T   0        // bf16 [384][128]  (gnn_w @ W_ih^T)^T rows
#define WS_WHH    98304    // bf16 [384][128]
#define WS_MW1    196608   // bf16 [128][128]
#define WS_MW2    229376   // bf16 [128][128]
#define WS_GB2    262144   // f32  [384]       W_ih @ gnn_b

__device__ __forceinline__ unsigned short f2bf(float f){
  union{float f; uint32_t u;} v; v.f = f;
  return (unsigned short)((v.u + 0x7FFFu + ((v.u>>16)&1u)) >> 16);
}
__device__ __forceinline__ float bf2f(unsigned short h){
  union{uint32_t u; float f;} v; v.u = ((uint32_t)h)<<16; return v.f;
}
__device__ __forceinline__ float fast_sigmoid(float x){
  float t = __builtin_amdgcn_exp2f(-1.442695041f*x);
  return __builtin_amdgcn_rcpf(1.0f + t);
}
__device__ __forceinline__ float fast_tanh(float x){
  float t = __builtin_amdgcn_exp2f(-2.885390082f*x);
  return 2.0f*__builtin_amdgcn_rcpf(1.0f + t) - 1.0f;
}
// XOR-swizzled row-major [128][128] bf16 LDS addressing. 16B chunks of 8 elems.
// chunk ^= (row&7) ^ ((row>>3)&1)<<1: all lane-varying contributions are pure
// XOR bits -> b128 row reads conflict-free (8-lane phases hit 32 distinct words)
// AND 16x16 u16 column-scatter covers 32 banks at exactly 2 lanes/word (free).
__device__ __forceinline__ uint32_t sw(uint32_t row, uint32_t col){
  return row*256u + ((((col>>3) ^ (row&7) ^ (((row>>3)&1u)<<1)) << 4) | ((col&7)<<1));
}

// ---------------- prep kernel: weight conversions + Gw2T + gb2 ----------------
extern "C" __global__ __launch_bounds__(128) void gnn_prep(
    const float* __restrict__ Wih, const float* __restrict__ Whh,
    const float* __restrict__ gnnw, const float* __restrict__ gnnb,
    const float* __restrict__ mW1, const float* __restrict__ mW2,
    unsigned short* __restrict__ gw2t, unsigned short* __restrict__ whhb,
    unsigned short* __restrict__ mw1b, unsigned short* __restrict__ mw2b,
    float* __restrict__ gb2)
{
  __shared__ float wg[128];
  const int b = blockIdx.x, t = threadIdx.x;
  if (b < 384){
    wg[t] = Wih[b*128 + t];
    __syncthreads();
    float acc = 0.f;
    for (int h=0; h<128; ++h) acc += wg[h] * gnnw[t*128 + h];
    gw2t[b*128 + t] = f2bf(acc);
    if (t == 0){
      float a2 = 0.f;
      for (int h=0; h<128; ++h) a2 += wg[h] * gnnb[h];
      gb2[b] = a2;
    }
  } else if (b < 416){
    int base = (b-384)*1536;
    for (int i=t; i<1536; i+=128) whhb[base+i] = f2bf(Whh[base+i]);
  } else if (b < 432){
    int base = (b-416)*1024;
    for (int i=t; i<1024; i+=128) mw1b[base+i] = f2bf(mW1[base+i]);
  } else if (b < 448){
    int base = (b-432)*1024;
    for (int i=t; i<1024; i+=128) mw2b[base+i] = f2bf(mW2[base+i]);
  }
}

// ---------------- main fused kernel: one 1024-thread block per sentence ----------------
extern "C" __global__ __launch_bounds__(1024) void gnn_main(
    const int* __restrict__ iv, const float* __restrict__ adj,
    const float* __restrict__ emb,
    const float* __restrict__ bih, const float* __restrict__ bhh,
    const float* __restrict__ mb1, const float* __restrict__ mb2,
    const float* __restrict__ mW3, const float* __restrict__ mb3,
    const __bf16* __restrict__ gw2t, const __bf16* __restrict__ whhb,
    const __bf16* __restrict__ mw1b, const __bf16* __restrict__ mw2b,
    const float* __restrict__ gb2, float* __restrict__ out)
{
  extern __shared__ char lds[];
  const int bs   = blockIdx.x;
  const int tid  = threadIdx.x;
  const int w    = tid >> 6;        // 0..15
  const int lane = tid & 63;
  const int n16  = lane & 15;
  const int q    = lane >> 4;
  const f32x4 zf4 = {0.f, 0.f, 0.f, 0.f};

  // wave roles
  const int hw = w >> 1, lc = w & 1;
  const int t0  = hw*16;            // stage-A t-tile / gate-upd h-block
  const int h0  = t0;
  const int lG0 = lc*64;            // gate/upd l-range [lG0, lG0+64)
  const int wr = w >> 2, wc = w & 3;
  const int tm0 = wr*32, lm0 = wc*32;   // MLP tile origins

  // ---- init: biases ----
  if (tid < 128){
    int h = tid;
    float* cb = (float*)(lds + LDS_CB + h*32);
    cb[0] = gb2[h]; cb[1] = gb2[128+h]; cb[2] = gb2[256+h];
    cb[3] = bih[h] + bhh[h];
    cb[4] = bih[128+h] + bhh[128+h];
    cb[5] = bih[256+h];
    cb[6] = bhh[256+h];
    cb[7] = 0.f;
  } else if (tid < 256){
    int t = tid - 128;
    *(float*)(lds + LDS_MB1 + t*4) = mb1[t];
    *(float*)(lds + LDS_MB2 + t*4) = mb2[t];
  }
  // ---- emb gather -> NFROW + NFT ----
  {
    const int l   = tid >> 3;
    const int hc8 = (tid & 7) * 16;
    const int row = iv[bs*128 + l];
    const float* src = emb + (size_t)row*128 + hc8;
    #pragma unroll
    for (int c=0; c<2; ++c){
      float4 f0 = *(const float4*)(src + c*8);
      float4 f1 = *(const float4*)(src + c*8 + 4);
      union{ bf16x8 v; unsigned short s8[8]; } u;
      u.s8[0]=f2bf(f0.x); u.s8[1]=f2bf(f0.y); u.s8[2]=f2bf(f0.z); u.s8[3]=f2bf(f0.w);
      u.s8[4]=f2bf(f1.x); u.s8[5]=f2bf(f1.y); u.s8[6]=f2bf(f1.z); u.s8[7]=f2bf(f1.w);
      *(bf16x8*)(lds + LDS_NFROW + sw(l, hc8 + c*8)) = u.v;
      #pragma unroll
      for (int j=0; j<8; ++j)
        *(unsigned short*)(lds + LDS_NFT + sw(hc8 + c*8 + j, l)) = u.s8[j];
    }
    // adjacency row sum (8 threads per row, 16 elems each)
    const float* ap = adj + (size_t)bs*16384 + l*128 + hc8;
    float s = 0.f;
    #pragma unroll
    for (int c=0; c<4; ++c){
      float4 f = *(const float4*)(ap + c*4);
      s += f.x + f.y + f.z + f.w;
    }
    s += __shfl_xor(s, 1);
    s += __shfl_xor(s, 2);
    s += __shfl_xor(s, 4);
    if ((tid & 7) == 0) *(float*)(lds + LDS_RSA + l*4) = s;
  }
  // ---- pack adjacency -> SAT (bf16, B-fragment order) ----
  {
    const float* abase = adj + (size_t)bs * 16384;
    #pragma unroll
    for (int k=0; k<2; ++k){
      int s   = k*1024 + tid;            // 0..2047 chunk-lane slots
      int sl  = s & 63;
      int chk = s >> 6;                  // = ltile*4 + kstep
      int ltg = chk >> 2, ks = chk & 3;
      int al  = ltg*16 + (sl & 15);      // B n-index -> adjacency row l
      int ak  = ks*32 + (sl >> 4) * 8;   // B k-index -> adjacency col l'
      const float* p = abase + al*128 + ak;
      float4 f0 = *(const float4*)(p);
      float4 f1 = *(const float4*)(p + 4);
      union{ bf16x8 v; unsigned short s8[8]; } u;
      u.s8[0]=f2bf(f0.x); u.s8[1]=f2bf(f0.y); u.s8[2]=f2bf(f0.z); u.s8[3]=f2bf(f0.w);
      u.s8[4]=f2bf(f1.x); u.s8[5]=f2bf(f1.y); u.s8[6]=f2bf(f1.z); u.s8[7]=f2bf(f1.w);
      *(bf16x8*)(lds + LDS_SAT + s*16) = u.v;
    }
  }
  __syncthreads();

  // gate weight row base pointers (wave-uniform + n16)
  const __bf16* gR = gw2t + (size_t)(h0       + n16) * 128;
  const __bf16* gZ = gw2t + (size_t)(h0 + 128 + n16) * 128;
  const __bf16* gN = gw2t + (size_t)(h0 + 256 + n16) * 128;
  const __bf16* hR = whhb + (size_t)(h0       + n16) * 128;
  const __bf16* hZ = whhb + (size_t)(h0 + 128 + n16) * 128;
  const __bf16* hN = whhb + (size_t)(h0 + 256 + n16) * 128;

  for (int it=0; it<10; ++it){
    // ===== stage A: P^T[t][l] = sum_l' nf^T[t][l'] * adj[l][l'] =====
    // A-op = nf^T (LDS), B-op = SAT (LDS, pre-packed bf16 fragments)
    f32x4 accA[4];
    #pragma unroll
    for (int j=0; j<4; ++j) accA[j] = zf4;
    for (int ks=0; ks<4; ++ks){
      bf16x8 af = *(const bf16x8*)(lds + LDS_NFT + sw(t0 + n16, ks*32 + q*8));
      #pragma unroll
      for (int j=0; j<4; ++j){
        int chunk = (lc*4 + j)*4 + ks;
        bf16x8 bfb = *(const bf16x8*)(lds + LDS_SAT + (chunk*64 + lane)*16);
        accA[j] = __builtin_amdgcn_mfma_f32_16x16x32_bf16(af, bfb, accA[j], 0,0,0);
      }
    }
    #pragma unroll
    for (int j=0; j<4; ++j){
      int l = lG0 + j*16 + n16;
      ushortx4 o4;
      #pragma unroll
      for (int r=0; r<4; ++r) o4[r] = f2bf(accA[j][r]);
      *(ushortx4*)(lds + LDS_P + sw(l, t0 + q*4)) = o4;   // P[l][t]
    }
    __syncthreads();

    // ===== gate matmuls: wave = 16 h-rows x 64 l-cols, k-full =====
    f32x4 aR[4], aZ[4], aGN[4], aHN[4];
    #pragma unroll
    for (int i=0; i<4; ++i){ aR[i]=zf4; aZ[i]=zf4; aGN[i]=zf4; aHN[i]=zf4; }
    for (int ks=0; ks<4; ++ks){
      int koff = ks*32 + q*8;
      bf16x8 f_gr = *(const bf16x8*)(gR + koff);
      bf16x8 f_gz = *(const bf16x8*)(gZ + koff);
      bf16x8 f_gn = *(const bf16x8*)(gN + koff);
      bf16x8 f_hr = *(const bf16x8*)(hR + koff);
      bf16x8 f_hz = *(const bf16x8*)(hZ + koff);
      bf16x8 f_hn = *(const bf16x8*)(hN + koff);
      #pragma unroll
      for (int lt=0; lt<4; ++lt){
        int l = lG0 + lt*16 + n16;
        bf16x8 bp = *(const bf16x8*)(lds + LDS_P     + sw(l, koff));
        bf16x8 bh = *(const bf16x8*)(lds + LDS_NFROW + sw(l, koff));
        aR[lt]  = __builtin_amdgcn_mfma_f32_16x16x32_bf16(f_gr, bp, aR[lt], 0,0,0);
        aZ[lt]  = __builtin_amdgcn_mfma_f32_16x16x32_bf16(f_gz, bp, aZ[lt], 0,0,0);
        aGN[lt] = __builtin_amdgcn_mfma_f32_16x16x32_bf16(f_gn, bp, aGN[lt], 0,0,0);
        aR[lt]  = __builtin_amdgcn_mfma_f32_16x16x32_bf16(f_hr, bh, aR[lt], 0,0,0);
        aZ[lt]  = __builtin_amdgcn_mfma_f32_16x16x32_bf16(f_hz, bh, aZ[lt], 0,0,0);
        aHN[lt] = __builtin_amdgcn_mfma_f32_16x16x32_bf16(f_hn, bh, aHN[lt], 0,0,0);
      }
    }
    __syncthreads();   // all gate reads of NFROW/P done before nf updates

    // ===== elementwise GRU update =====
    f32x4 cbA[4], cbB[4];
    #pragma unroll
    for (int r=0; r<4; ++r){
      int h = h0 + q*4 + r;
      cbA[r] = *(const f32x4*)(lds + LDS_CB + h*32);
      cbB[r] = *(const f32x4*)(lds + LDS_CB + h*32 + 16);
    }
    #pragma unroll
    for (int lt=0; lt<4; ++lt){
      int l = lG0 + lt*16 + n16;
      float rs = *(const float*)(lds + LDS_RSA + l*4);
      uint32_t a_nf = sw(l, h0 + q*4);
      ushortx4 old4 = *(const ushortx4*)(lds + LDS_NFROW + a_nf);
      ushortx4 new4;
      #pragma unroll
      for (int r=0; r<4; ++r){
        float xr = aR[lt][r] + rs*cbA[r][0] + cbA[r][3];
        float xz = aZ[lt][r] + rs*cbA[r][1] + cbB[r][0];
        float rg = fast_sigmoid(xr);
        float zg = fast_sigmoid(xz);
        float xn = (aGN[lt][r] + rs*cbA[r][2] + cbB[r][1]) + rg*(aHN[lt][r] + cbB[r][2]);
        float ng = fast_tanh(xn);
        float hv = bf2f(old4[r]);
        new4[r] = f2bf(ng + zg*(hv - ng));
      }
      *(ushortx4*)(lds + LDS_NFROW + a_nf) = new4;
      #pragma unroll
      for (int r=0; r<4; ++r)
        *(unsigned short*)(lds + LDS_NFT + sw(h0 + q*4 + r, l)) = new4[r];
    }
    __syncthreads();
  }

  // ===== MLP: h1 = tanh(nf@mW1^T + mb1) -> LDS_P =====
  {
    f32x4 acc[2][2];
    #pragma unroll
    for (int a=0; a<2; ++a){ acc[a][0] = zf4; acc[a][1] = zf4; }
    for (int ks=0; ks<4; ++ks){
      int koff = ks*32 + q*8;
      bf16x8 af[2];
      #pragma unroll
      for (int tt=0; tt<2; ++tt)
        af[tt] = *(const bf16x8*)(mw1b + (size_t)(tm0 + tt*16 + n16)*128 + koff);
      #pragma unroll
      for (int lb=0; lb<2; ++lb){
        int l = lm0 + lb*16 + n16;
        bf16x8 bb = *(const bf16x8*)(lds + LDS_NFROW + sw(l, koff));
        #pragma unroll
        for (int tt=0; tt<2; ++tt)
          acc[tt][lb] = __builtin_amdgcn_mfma_f32_16x16x32_bf16(af[tt], bb, acc[tt][lb], 0,0,0);
      }
    }
    #pragma unroll
    for (int tt=0; tt<2; ++tt){
      #pragma unroll
      for (int lb=0; lb<2; ++lb){
        int l  = lm0 + lb*16 + n16;
        int ob = tm0 + tt*16 + q*4;
        ushortx4 o4;
        #pragma unroll
        for (int r=0; r<4; ++r){
          float bsv = *(const float*)(lds + LDS_MB1 + (ob + r)*4);
          o4[r] = f2bf(fast_tanh(acc[tt][lb][r] + bsv));
        }
        *(ushortx4*)(lds + LDS_P + sw(l, ob)) = o4;   // P-region no longer read by anyone until h2
      }
    }
  }
  __syncthreads();

  // ===== h2 = tanh(h1@mW2^T + mb2) -> LDS_NFT region =====
  {
    f32x4 acc[2][2];
    #pragma unroll
    for (int a=0; a<2; ++a){ acc[a][0] = zf4; acc[a][1] = zf4; }
    for (int ks=0; ks<4; ++ks){
      int koff = ks*32 + q*8;
      bf16x8 af[2];
      #pragma unroll
      for (int tt=0; tt<2; ++tt)
        af[tt] = *(const bf16x8*)(mw2b + (size_t)(tm0 + tt*16 + n16)*128 + koff);
      #pragma unroll
      for (int lb=0; lb<2; ++lb){
        int l = lm0 + lb*16 + n16;
        bf16x8 bb = *(const bf16x8*)(lds + LDS_P + sw(l, koff));
        #pragma unroll
        for (int tt=0; tt<2; ++tt)
          acc[tt][lb] = __builtin_amdgcn_mfma_f32_16x16x32_bf16(af[tt], bb, acc[tt][lb], 0,0,0);
      }
    }
    #pragma unroll
    for (int tt=0; tt<2; ++tt){
      #pragma unroll
      for (int lb=0; lb<2; ++lb){
        int l  = lm0 + lb*16 + n16;
        int ob = tm0 + tt*16 + q*4;
        ushortx4 o4;
        #pragma unroll
        for (int r=0; r<4; ++r){
          float bsv = *(const float*)(lds + LDS_MB2 + (ob + r)*4);
          o4[r] = f2bf(fast_tanh(acc[tt][lb][r] + bsv));
        }
        *(ushortx4*)(lds + LDS_NFT + sw(l, ob)) = o4;
      }
    }
  }
  __syncthreads();

  // ===== final: score[l] = tanh(h2[l]·mW3 + mb3) =====
  {
    int l = tid >> 3, p8 = tid & 7;
    float dot = 0.f;
    #pragma unroll
    for (int c=0; c<2; ++c){
      int o = p8*16 + c*8;
      union{ bf16x8 v; unsigned short s8[8]; } u;
      u.v = *(const bf16x8*)(lds + LDS_NFT + sw(l, o));
      float4 w0 = *(const float4*)(mW3 + o);
      float4 w1 = *(const float4*)(mW3 + o + 4);
      dot += bf2f(u.s8[0])*w0.x + bf2f(u.s8[1])*w0.y + bf2f(u.s8[2])*w0.z + bf2f(u.s8[3])*w0.w
           + bf2f(u.s8[4])*w1.x + bf2f(u.s8[5])*w1.y + bf2f(u.s8[6])*w1.z + bf2f(u.s8[7])*w1.w;
    }
    dot += __shfl_xor(dot, 1);
    dot += __shfl_xor(dot, 2);
    dot += __shfl_xor(dot, 4);
    if (p8 == 0) out[bs*128 + l] = fast_tanh(dot + mb3[0]);
  }
}

extern "C" void kernel_launch(void* const* d_in, const int* in_sizes, int n_in,
                              void* d_out, int out_size, void* d_ws, size_t ws_size,
                              hipStream_t stream)
{
  const int*   iv   = (const int*)  d_in[0];
  const float* adj  = (const float*)d_in[1];
  const float* emb  = (const float*)d_in[2];
  const float* gnnw = (const float*)d_in[3];
  const float* gnnb = (const float*)d_in[4];
  const float* Wih  = (const float*)d_in[5];
  const float* Whh  = (const float*)d_in[6];
  const float* bihp = (const float*)d_in[7];
  const float* bhhp = (const float*)d_in[8];
  const float* mW1  = (const float*)d_in[9];
  const float* mb1  = (const float*)d_in[10];
  const float* mW2  = (const float*)d_in[11];
  const float* mb2  = (const float*)d_in[12];
  const float* mW3  = (const float*)d_in[13];
  const float* mb3  = (const float*)d_in[14];
  float* out = (float*)d_out;

  char* ws = (char*)d_ws;
  unsigned short* gw2t_w = (unsigned short*)(ws + WS_GW2T);
  unsigned short* whhb_w = (unsigned short*)(ws + WS_WHH);
  unsigned short* mw1b_w = (unsigned short*)(ws + WS_MW1);
  unsigned short* mw2b_w = (unsigned short*)(ws + WS_MW2);
  float*          gb2_w  = (float*)(ws + WS_GB2);

  hipFuncSetAttribute((const void*)gnn_main,
                      hipFuncAttributeMaxDynamicSharedMemorySize, LDS_TOTAL);

  gnn_prep<<<448, 128, 0, stream>>>(Wih, Whh, gnnw, gnnb, mW1, mW2,
                                    gw2t_w, whhb_w, mw1b_w, mw2b_w, gb2_w);

  int nbs = in_sizes[0] / 128;  // B*S = 2048 sentences
  gnn_main<<<nbs, 1024, LDS_TOTAL, stream>>>(
      iv, adj, emb, bihp, bhhp, mb1, mb2, mW3, mb3,
      (const __bf16*)gw2t_w, (const __bf16*)whhb_w,
      (const __bf16*)mw1b_w, (const __bf16*)mw2b_w, gb2_w, out);
}